// Round 2
// baseline (437.052 us; speedup 1.0000x reference)
//
#include <hip/hip_runtime.h>

// WindowAttention fused kernel (Swin, B_=4096, N=64, C=128, H=4, d=32).
// All float tensors are fp32 in HBM (per reference dtypes); compute uses
// bf16 MFMA with fp32 accumulation. One block = one window, one wave = one
// head. LDS (exactly 64KB):
//   [0,16384)        : XY  = x then y, [64][128] bf16, 16B-chunk XOR swizzle
//   per wave Wb=16384+h*12288:
//     [Wb, Wb+4096)   : Q [64][32] bf16 (chunk ^ (r>>2)&3)
//     [Wb+4096,+8192) : K [64][32] bf16 (same swizzle)
//     [Wb, Wb+8192)   : P [64][64] bf16 (chunk ^ r&7) -- overlays dead Q+K
//     [Wb+8192,+12288): Vt [32][64] bf16 (chunk ^ dd&7)
// Fragment layouts (guide §3, m89/m91-verified):
//   A: lane holds A[m=lane&15][k=quad*8+j]   (8 consecutive k -> b128)
//   B: lane holds B[k=quad*8+j][n=lane&15]
//   C/D: col(n)=lane&15, row(m)=quad*4+reg
// softmax in base 2: log2e folded into Q-scale and into (rpb+mask).

typedef __bf16 bf16x8 __attribute__((ext_vector_type(8)));
typedef __bf16 bf16x4 __attribute__((ext_vector_type(4)));
typedef float f32x4 __attribute__((ext_vector_type(4)));

#define LOG2E 1.4426950408889634f
#define QSCALE (0.17677669529663687f * 1.4426950408889634f)  // d^-0.5 * log2e

static __device__ __forceinline__ bf16x8 cvt8(const float* __restrict__ p) {
  bf16x8 r;
#pragma unroll
  for (int i = 0; i < 8; ++i) r[i] = (__bf16)p[i];
  return r;
}

// byte offsets into smem
static __device__ __forceinline__ int xaddr(int r, int c) {       // 64x128
  return (r << 8) + ((((c >> 3) ^ (r & 7)) << 4)) + ((c & 7) << 1);
}
static __device__ __forceinline__ int qaddr(int r, int c) {       // 64x32
  return (r << 6) + ((((c >> 3) ^ ((r >> 2) & 3)) << 4)) + ((c & 7) << 1);
}
static __device__ __forceinline__ int paddr(int r, int c) {       // 64x64
  return (r << 7) + ((((c >> 3) ^ (r & 7)) << 4)) + ((c & 7) << 1);
}
static __device__ __forceinline__ int vtaddr(int dd, int m) {     // 32x64 (V^T)
  return (dd << 7) + ((((m >> 3) ^ (dd & 7)) << 4)) + ((m & 7) << 1);
}

#define MFMA16(acc, afr, bfr) \
  acc = __builtin_amdgcn_mfma_f32_16x16x32_bf16(afr, bfr, acc, 0, 0, 0)

__global__ __launch_bounds__(256, 2)
void winattn_kernel(const float* __restrict__ xg,
                    const float* __restrict__ wq,
                    const float* __restrict__ bq,
                    const float* __restrict__ wkv,
                    const float* __restrict__ bkv,
                    const float* __restrict__ bt,
                    const float* __restrict__ wp,
                    const float* __restrict__ bp,
                    const float* __restrict__ mask,
                    const int* __restrict__ ri,
                    float* __restrict__ out) {
  __shared__ char smem[65536];
  const int b = blockIdx.x;
  const int tid = (int)threadIdx.x;
  const int h = tid >> 6;          // head / wave
  const int lane = tid & 63;
  const int q4 = lane >> 4;        // quad
  const int li = lane & 15;
  const int Wb = 16384 + h * 12288;
  const int Qb = Wb, Kb = Wb + 4096, Pb = Wb, Vb = Wb + 8192;

  // ---- stage x window (64x128 fp32 -> bf16 in LDS) ----
  {
    const float* xw = xg + b * 8192;
#pragma unroll
    for (int rep = 0; rep < 4; ++rep) {
      int chunk = rep * 256 + tid;       // 1024 x 8-element chunks
      int r = chunk >> 4, cc = chunk & 15;
      bf16x8 v = cvt8(xw + r * 128 + cc * 8);
      *(bf16x8*)(smem + xaddr(r, cc * 8)) = v;
    }
  }
  __syncthreads();

  // ---- step 1: Q/K/V for this head (64x32 each, K=128) ----
  {
    f32x4 aq[4][2] = {}; f32x4 ak[4][2] = {}; f32x4 av[4][2] = {};
#pragma unroll
    for (int kk = 0; kk < 4; ++kk) {
      bf16x8 a[4];
#pragma unroll
      for (int ti = 0; ti < 4; ++ti)
        a[ti] = *(const bf16x8*)(smem + xaddr(ti * 16 + li, kk * 32 + q4 * 8));
#pragma unroll
      for (int tj = 0; tj < 2; ++tj) {
        int col = h * 32 + tj * 16 + li;
        int ko = kk * 32 + q4 * 8;
        bf16x8 wbq = cvt8(wq + col * 128 + ko);
        bf16x8 wbk = cvt8(wkv + col * 128 + ko);
        bf16x8 wbv = cvt8(wkv + (col + 128) * 128 + ko);
#pragma unroll
        for (int ti = 0; ti < 4; ++ti) {
          MFMA16(aq[ti][tj], a[ti], wbq);
          MFMA16(ak[ti][tj], a[ti], wbk);
          MFMA16(av[ti][tj], a[ti], wbv);
        }
      }
    }
    // add biases, convert, store Q (scaled), K, Vt to wave-private LDS
#pragma unroll
    for (int tj = 0; tj < 2; ++tj) {
      int col = h * 32 + tj * 16 + li;
      float bqv = bq[col];
      float bkk = bkv[col];
      float bvv = bkv[col + 128];
      int lc = tj * 16 + li;  // local col 0..31
#pragma unroll
      for (int ti = 0; ti < 4; ++ti) {
        __bf16 qs[4], ks[4], vs[4];
#pragma unroll
        for (int rr = 0; rr < 4; ++rr) {
          qs[rr] = (__bf16)((aq[ti][tj][rr] + bqv) * QSCALE);
          ks[rr] = (__bf16)(ak[ti][tj][rr] + bkk);
          vs[rr] = (__bf16)(av[ti][tj][rr] + bvv);
        }
#pragma unroll
        for (int rr = 0; rr < 4; ++rr) {
          int row = ti * 16 + q4 * 4 + rr;
          *(__bf16*)(smem + Qb + qaddr(row, lc)) = qs[rr];
          *(__bf16*)(smem + Kb + qaddr(row, lc)) = ks[rr];
        }
        int m0 = ti * 16 + q4 * 4;            // 4 consecutive m -> one b64
        bf16x4 vv = { vs[0], vs[1], vs[2], vs[3] };
        *(bf16x4*)(smem + Vb + vtaddr(lc, m0)) = vv;
      }
    }
  }
  asm volatile("s_waitcnt lgkmcnt(0)" ::: "memory");

  // ---- bias tile: log2e*(rel-pos-bias gather + window mask), C-layout ----
  float bias[4][4][4];
  {
    const float* mw = mask + b * 4096;
#pragma unroll
    for (int ti = 0; ti < 4; ++ti)
#pragma unroll
      for (int rr = 0; rr < 4; ++rr) {
        int n = ti * 16 + q4 * 4 + rr;
#pragma unroll
        for (int tj = 0; tj < 4; ++tj) {
          int m = tj * 16 + li;
          int idx = ri[n * 64 + m];
          bias[ti][tj][rr] = LOG2E * (bt[idx * 4 + h] + mw[n * 64 + m]);
        }
      }
  }

  // ---- step 2: S = Q K^T (+bias via MFMA C operand), 4x4 tiles, K=32 ----
  f32x4 S[4][4];
  {
    bf16x8 qf[4], kf[4];
#pragma unroll
    for (int t = 0; t < 4; ++t) {
      qf[t] = *(const bf16x8*)(smem + Qb + qaddr(t * 16 + li, q4 * 8));
      kf[t] = *(const bf16x8*)(smem + Kb + qaddr(t * 16 + li, q4 * 8));
    }
#pragma unroll
    for (int ti = 0; ti < 4; ++ti)
#pragma unroll
      for (int tj = 0; tj < 4; ++tj) {
        f32x4 c = { bias[ti][tj][0], bias[ti][tj][1],
                    bias[ti][tj][2], bias[ti][tj][3] };
        S[ti][tj] = __builtin_amdgcn_mfma_f32_16x16x32_bf16(qf[ti], kf[tj], c, 0, 0, 0);
      }
  }

  // ---- step 3: row softmax (base 2), deferred 1/l normalization ----
  float rinv[4][4];
#pragma unroll
  for (int ti = 0; ti < 4; ++ti)
#pragma unroll
    for (int rr = 0; rr < 4; ++rr) {
      float mx = fmaxf(fmaxf(S[ti][0][rr], S[ti][1][rr]),
                       fmaxf(S[ti][2][rr], S[ti][3][rr]));
      mx = fmaxf(mx, __shfl_xor(mx, 1));
      mx = fmaxf(mx, __shfl_xor(mx, 2));
      mx = fmaxf(mx, __shfl_xor(mx, 4));
      mx = fmaxf(mx, __shfl_xor(mx, 8));
      float s = 0.f;
#pragma unroll
      for (int tj = 0; tj < 4; ++tj) {
        float e = exp2f(S[ti][tj][rr] - mx);
        S[ti][tj][rr] = e;
        s += e;
      }
      s += __shfl_xor(s, 1);
      s += __shfl_xor(s, 2);
      s += __shfl_xor(s, 4);
      s += __shfl_xor(s, 8);
      rinv[ti][rr] = __builtin_amdgcn_rcpf(s);
    }

  // ---- step 4: P (bf16) -> LDS (overlays dead Q/K) ----
#pragma unroll
  for (int ti = 0; ti < 4; ++ti)
#pragma unroll
    for (int rr = 0; rr < 4; ++rr) {
      int n = ti * 16 + q4 * 4 + rr;
#pragma unroll
      for (int tj = 0; tj < 4; ++tj) {
        int m = tj * 16 + li;
        *(__bf16*)(smem + Pb + paddr(n, m)) = (__bf16)S[ti][tj][rr];
      }
    }
  asm volatile("s_waitcnt lgkmcnt(0)" ::: "memory");

  // ---- step 5: O = P V (4x2 tiles, K=64) ----
  f32x4 O[4][2] = {};
#pragma unroll
  for (int ks = 0; ks < 2; ++ks) {
    bf16x8 pf[4], vf[2];
#pragma unroll
    for (int ti = 0; ti < 4; ++ti)
      pf[ti] = *(const bf16x8*)(smem + Pb + paddr(ti * 16 + li, ks * 32 + q4 * 8));
#pragma unroll
    for (int tj = 0; tj < 2; ++tj)
      vf[tj] = *(const bf16x8*)(smem + Vb + vtaddr(tj * 16 + li, ks * 32 + q4 * 8));
#pragma unroll
    for (int ti = 0; ti < 4; ++ti)
#pragma unroll
      for (int tj = 0; tj < 2; ++tj)
        MFMA16(O[ti][tj], pf[ti], vf[tj]);
  }

  // ---- step 6: y = O * (1/l) into XY buffer (x is dead after barrier) ----
  __syncthreads();
#pragma unroll
  for (int ti = 0; ti < 4; ++ti)
#pragma unroll
    for (int tj = 0; tj < 2; ++tj)
#pragma unroll
      for (int rr = 0; rr < 4; ++rr) {
        int row = ti * 16 + q4 * 4 + rr;
        int col = h * 32 + tj * 16 + li;
        *(__bf16*)(smem + xaddr(row, col)) = (__bf16)(O[ti][tj][rr] * rinv[ti][rr]);
      }
  __syncthreads();

  // ---- step 7: out = y @ wproj^T + bproj (fp32 stores) ----
  {
    f32x4 acc[4][2] = {};
#pragma unroll
    for (int kk = 0; kk < 4; ++kk) {
      bf16x8 a[4];
#pragma unroll
      for (int ti = 0; ti < 4; ++ti)
        a[ti] = *(const bf16x8*)(smem + xaddr(ti * 16 + li, kk * 32 + q4 * 8));
#pragma unroll
      for (int tj = 0; tj < 2; ++tj) {
        int col = h * 32 + tj * 16 + li;
        bf16x8 wb = cvt8(wp + col * 128 + kk * 32 + q4 * 8);
#pragma unroll
        for (int ti = 0; ti < 4; ++ti)
          MFMA16(acc[ti][tj], a[ti], wb);
      }
    }
    float* ow = out + b * 8192;
#pragma unroll
    for (int tj = 0; tj < 2; ++tj) {
      int col = h * 32 + tj * 16 + li;
      float bpv = bp[col];
#pragma unroll
      for (int ti = 0; ti < 4; ++ti)
#pragma unroll
        for (int rr = 0; rr < 4; ++rr) {
          int row = ti * 16 + q4 * 4 + rr;
          ow[row * 128 + col] = acc[ti][tj][rr] + bpv;
        }
    }
  }
}

extern "C" void kernel_launch(void* const* d_in, const int* in_sizes, int n_in,
                              void* d_out, int out_size, void* d_ws, size_t ws_size,
                              hipStream_t stream) {
  (void)in_sizes; (void)n_in; (void)d_ws; (void)ws_size; (void)out_size;
  winattn_kernel<<<4096, 256, 0, stream>>>(
      (const float*)d_in[0],  // x
      (const float*)d_in[1],  // wq
      (const float*)d_in[2],  // bq
      (const float*)d_in[3],  // wkv
      (const float*)d_in[4],  // bkv
      (const float*)d_in[5],  // bias_table
      (const float*)d_in[6],  // wproj
      (const float*)d_in[7],  // bproj
      (const float*)d_in[8],  // mask
      (const int*)d_in[9],    // rel_index
      (float*)d_out);
}

// Round 3
// 337.244 us; speedup vs baseline: 1.2960x; 1.2960x over previous
//
#include <hip/hip_runtime.h>

// WindowAttention fused (Swin, B_=4096, N=64, C=128, H=4, d=32), fp32 I/O,
// bf16 MFMA compute. Two kernels per launch:
//   prep_kernel: packs weights (fp32 -> bf16, B-fragment lane order) and the
//     block-invariant rel-pos-bias (C-layout lane order, x log2e) into d_ws.
//     ws layout: [0,32K) wqP | [32K,64K) wkP | [64K,96K) wvP | [96K,128K) wpP
//                [128K,192K) rpb packed f32x4
//   winattn_kernel: one block = one window, one wave = one head.
// LDS (64KB): [0,16K) x/y tile (XOR-swizzled bf16); per-wave 12KB Q/K/P/Vt.
// Fragment layouts (m89/m91-verified):
//   A: lane holds A[m=lane&15][k=quad*8+j]
//   B: lane holds B[k=quad*8+j][n=lane&15]
//   C/D: col(n)=lane&15, row(m)=quad*4+reg
// softmax in base 2; log2e folded into Q-scale, rpb, and mask-add.

typedef __bf16 bf16x8 __attribute__((ext_vector_type(8)));
typedef __bf16 bf16x4 __attribute__((ext_vector_type(4)));
typedef float f32x4 __attribute__((ext_vector_type(4)));

#define LOG2E 1.4426950408889634f
#define QSCALE (0.17677669529663687f * 1.4426950408889634f)  // d^-0.5 * log2e

// ---------------- prep kernel ----------------
__global__ __launch_bounds__(256)
void prep_kernel(const float* __restrict__ wq,
                 const float* __restrict__ wkv,
                 const float* __restrict__ wp,
                 const float* __restrict__ bt,
                 const int* __restrict__ ri,
                 char* __restrict__ ws) {
  int t = blockIdx.x * 256 + (int)threadIdx.x;  // 0..24575
  if (t < 8192) {
    // pack one 16B bf16x8 fragment chunk of one weight stream
    int s = t >> 11;            // 0=wq 1=wk 2=wv 3=wp
    int c = t & 2047;
    int lane = c & 63, kk = (c >> 6) & 3, ct = c >> 8;  // coltile 0..7
    int li = lane & 15, q4 = lane >> 4;
    int col = ct * 16 + li;
    int ko = kk * 32 + q4 * 8;
    const float* src = (s == 0) ? (wq + col * 128 + ko)
                     : (s == 1) ? (wkv + col * 128 + ko)
                     : (s == 2) ? (wkv + (col + 128) * 128 + ko)
                                : (wp + col * 128 + ko);
    bf16x8 v;
#pragma unroll
    for (int i = 0; i < 8; ++i) v[i] = (__bf16)src[i];
    *(bf16x8*)(ws + s * 32768 + c * 16) = v;
  } else {
    // rel-pos-bias, C-layout lane order, x log2e
    int c = t - 8192;  // 0..16383
    int lane = c & 63, tj = (c >> 6) & 3, ti = (c >> 8) & 3, h = (c >> 10) & 3;
    int li = lane & 15, q4 = lane >> 4;
    int m = tj * 16 + li;
    f32x4 r;
#pragma unroll
    for (int rr = 0; rr < 4; ++rr) {
      int n = ti * 16 + q4 * 4 + rr;
      r[rr] = LOG2E * bt[ri[n * 64 + m] * 4 + h];
    }
    *(f32x4*)(ws + 131072 + c * 16) = r;
  }
}

// ---------------- main kernel ----------------
static __device__ __forceinline__ bf16x8 cvt8(const float* __restrict__ p) {
  bf16x8 r;
#pragma unroll
  for (int i = 0; i < 8; ++i) r[i] = (__bf16)p[i];
  return r;
}

// byte offsets into smem
static __device__ __forceinline__ int xaddr(int r, int c) {       // 64x128
  return (r << 8) + ((((c >> 3) ^ (r & 7)) << 4)) + ((c & 7) << 1);
}
static __device__ __forceinline__ int qaddr(int r, int c) {       // 64x32
  return (r << 6) + ((((c >> 3) ^ ((r >> 2) & 3)) << 4)) + ((c & 7) << 1);
}
static __device__ __forceinline__ int paddr(int r, int c) {       // 64x64
  return (r << 7) + ((((c >> 3) ^ (r & 7)) << 4)) + ((c & 7) << 1);
}
static __device__ __forceinline__ int vtaddr(int dd, int m) {     // 32x64 (V^T)
  return (dd << 7) + ((((m >> 3) ^ (dd & 7)) << 4)) + ((m & 7) << 1);
}

#define MFMA16(acc, afr, bfr) \
  acc = __builtin_amdgcn_mfma_f32_16x16x32_bf16(afr, bfr, acc, 0, 0, 0)

__global__ __launch_bounds__(256, 2)
void winattn_kernel(const float* __restrict__ xg,
                    const float* __restrict__ bq,
                    const float* __restrict__ bkv,
                    const float* __restrict__ bp,
                    const float* __restrict__ mask,
                    const char* __restrict__ ws,
                    float* __restrict__ out) {
  __shared__ char smem[65536];
  const int b = blockIdx.x;
  const int tid = (int)threadIdx.x;
  const int h = tid >> 6;          // head / wave
  const int lane = tid & 63;
  const int q4 = lane >> 4;        // quad
  const int li = lane & 15;
  const int Wb = 16384 + h * 12288;
  const int Qb = Wb, Kb = Wb + 4096, Pb = Wb, Vb = Wb + 8192;
  const bf16x8* __restrict__ wqP = (const bf16x8*)(ws);
  const bf16x8* __restrict__ wkP = (const bf16x8*)(ws + 32768);
  const bf16x8* __restrict__ wvP = (const bf16x8*)(ws + 65536);
  const bf16x8* __restrict__ wpP = (const bf16x8*)(ws + 98304);
  const f32x4* __restrict__ rpbP = (const f32x4*)(ws + 131072);

  // ---- stage x window (64x128 fp32 -> bf16 in LDS, coalesced) ----
  {
    const float* xw = xg + b * 8192;
#pragma unroll
    for (int rep = 0; rep < 4; ++rep) {
      int chunk = rep * 256 + tid;       // 1024 x 8-element chunks
      int r = chunk >> 4, cc = chunk & 15;
      bf16x8 v = cvt8(xw + r * 128 + cc * 8);
      *(bf16x8*)(smem + xaddr(r, cc * 8)) = v;
    }
  }
  __syncthreads();

  // ---- step 1: Q/K/V for this head (64x32 each, K=128) ----
  {
    f32x4 aq[4][2] = {}; f32x4 ak[4][2] = {}; f32x4 av[4][2] = {};
#pragma unroll
    for (int kk = 0; kk < 4; ++kk) {
      bf16x8 a[4];
#pragma unroll
      for (int ti = 0; ti < 4; ++ti)
        a[ti] = *(const bf16x8*)(smem + xaddr(ti * 16 + li, kk * 32 + q4 * 8));
#pragma unroll
      for (int tj = 0; tj < 2; ++tj) {
        int wi = ((h * 2 + tj) * 4 + kk) * 64 + lane;   // coalesced packed frag
        bf16x8 wbq = wqP[wi];
        bf16x8 wbk = wkP[wi];
        bf16x8 wbv = wvP[wi];
#pragma unroll
        for (int ti = 0; ti < 4; ++ti) {
          MFMA16(aq[ti][tj], a[ti], wbq);
          MFMA16(ak[ti][tj], a[ti], wbk);
          MFMA16(av[ti][tj], a[ti], wbv);
        }
      }
    }
    // add biases, convert, store Q (scaled), K, Vt to wave-private LDS
#pragma unroll
    for (int tj = 0; tj < 2; ++tj) {
      int col = h * 32 + tj * 16 + li;
      float bqv = bq[col];
      float bkk = bkv[col];
      float bvv = bkv[col + 128];
      int lc = tj * 16 + li;  // local col 0..31
#pragma unroll
      for (int ti = 0; ti < 4; ++ti) {
        __bf16 qs[4], ks[4], vs[4];
#pragma unroll
        for (int rr = 0; rr < 4; ++rr) {
          qs[rr] = (__bf16)((aq[ti][tj][rr] + bqv) * QSCALE);
          ks[rr] = (__bf16)(ak[ti][tj][rr] + bkk);
          vs[rr] = (__bf16)(av[ti][tj][rr] + bvv);
        }
#pragma unroll
        for (int rr = 0; rr < 4; ++rr) {
          int row = ti * 16 + q4 * 4 + rr;
          *(__bf16*)(smem + Qb + qaddr(row, lc)) = qs[rr];
          *(__bf16*)(smem + Kb + qaddr(row, lc)) = ks[rr];
        }
        int m0 = ti * 16 + q4 * 4;            // 4 consecutive m -> one b64
        bf16x4 vv = { vs[0], vs[1], vs[2], vs[3] };
        *(bf16x4*)(smem + Vb + vtaddr(lc, m0)) = vv;
      }
    }
  }
  asm volatile("s_waitcnt lgkmcnt(0)" ::: "memory");

  // ---- bias tile: rpb (prepacked, coalesced) + log2e * mask ----
  float bias[4][4][4];
  {
    const float* mw = mask + b * 4096;
#pragma unroll
    for (int ti = 0; ti < 4; ++ti)
#pragma unroll
      for (int tj = 0; tj < 4; ++tj) {
        f32x4 rv = rpbP[((h * 4 + ti) * 4 + tj) * 64 + lane];
        int m = tj * 16 + li;
#pragma unroll
        for (int rr = 0; rr < 4; ++rr) {
          int n = ti * 16 + q4 * 4 + rr;
          bias[ti][tj][rr] = fmaf(LOG2E, mw[n * 64 + m], rv[rr]);
        }
      }
  }

  // ---- step 2: S = Q K^T (+bias via MFMA C operand), 4x4 tiles, K=32 ----
  f32x4 S[4][4];
  {
    bf16x8 qf[4], kf[4];
#pragma unroll
    for (int t = 0; t < 4; ++t) {
      qf[t] = *(const bf16x8*)(smem + Qb + qaddr(t * 16 + li, q4 * 8));
      kf[t] = *(const bf16x8*)(smem + Kb + qaddr(t * 16 + li, q4 * 8));
    }
#pragma unroll
    for (int ti = 0; ti < 4; ++ti)
#pragma unroll
      for (int tj = 0; tj < 4; ++tj) {
        f32x4 c = { bias[ti][tj][0], bias[ti][tj][1],
                    bias[ti][tj][2], bias[ti][tj][3] };
        S[ti][tj] = __builtin_amdgcn_mfma_f32_16x16x32_bf16(qf[ti], kf[tj], c, 0, 0, 0);
      }
  }

  // ---- step 3: row softmax (base 2), deferred 1/l normalization ----
  float rinv[4][4];
#pragma unroll
  for (int ti = 0; ti < 4; ++ti)
#pragma unroll
    for (int rr = 0; rr < 4; ++rr) {
      float mx = fmaxf(fmaxf(S[ti][0][rr], S[ti][1][rr]),
                       fmaxf(S[ti][2][rr], S[ti][3][rr]));
      mx = fmaxf(mx, __shfl_xor(mx, 1));
      mx = fmaxf(mx, __shfl_xor(mx, 2));
      mx = fmaxf(mx, __shfl_xor(mx, 4));
      mx = fmaxf(mx, __shfl_xor(mx, 8));
      float s = 0.f;
#pragma unroll
      for (int tj = 0; tj < 4; ++tj) {
        float e = __builtin_amdgcn_exp2f(S[ti][tj][rr] - mx);
        S[ti][tj][rr] = e;
        s += e;
      }
      s += __shfl_xor(s, 1);
      s += __shfl_xor(s, 2);
      s += __shfl_xor(s, 4);
      s += __shfl_xor(s, 8);
      rinv[ti][rr] = __builtin_amdgcn_rcpf(s);
    }

  // ---- step 4: P (bf16) -> LDS (overlays dead Q/K) ----
#pragma unroll
  for (int ti = 0; ti < 4; ++ti)
#pragma unroll
    for (int rr = 0; rr < 4; ++rr) {
      int n = ti * 16 + q4 * 4 + rr;
#pragma unroll
      for (int tj = 0; tj < 4; ++tj) {
        int m = tj * 16 + li;
        *(__bf16*)(smem + Pb + paddr(n, m)) = (__bf16)S[ti][tj][rr];
      }
    }
  asm volatile("s_waitcnt lgkmcnt(0)" ::: "memory");

  // ---- step 5: O = P V (4x2 tiles, K=64) ----
  f32x4 O[4][2] = {};
#pragma unroll
  for (int ks = 0; ks < 2; ++ks) {
    bf16x8 pf[4], vf[2];
#pragma unroll
    for (int ti = 0; ti < 4; ++ti)
      pf[ti] = *(const bf16x8*)(smem + Pb + paddr(ti * 16 + li, ks * 32 + q4 * 8));
#pragma unroll
    for (int tj = 0; tj < 2; ++tj)
      vf[tj] = *(const bf16x8*)(smem + Vb + vtaddr(tj * 16 + li, ks * 32 + q4 * 8));
#pragma unroll
    for (int ti = 0; ti < 4; ++ti)
#pragma unroll
      for (int tj = 0; tj < 2; ++tj)
        MFMA16(O[ti][tj], pf[ti], vf[tj]);
  }

  // ---- step 6: y = O * (1/l) into XY buffer (x is dead after barrier) ----
  __syncthreads();
#pragma unroll
  for (int ti = 0; ti < 4; ++ti)
#pragma unroll
    for (int tj = 0; tj < 2; ++tj)
#pragma unroll
      for (int rr = 0; rr < 4; ++rr) {
        int row = ti * 16 + q4 * 4 + rr;
        int col = h * 32 + tj * 16 + li;
        *(__bf16*)(smem + xaddr(row, col)) = (__bf16)(O[ti][tj][rr] * rinv[ti][rr]);
      }
  __syncthreads();

  // ---- step 7: out = y @ wproj^T + bproj (fp32 stores) ----
  {
    f32x4 acc[4][2] = {};
#pragma unroll
    for (int kk = 0; kk < 4; ++kk) {
      bf16x8 a[4];
#pragma unroll
      for (int ti = 0; ti < 4; ++ti)
        a[ti] = *(const bf16x8*)(smem + xaddr(ti * 16 + li, kk * 32 + q4 * 8));
#pragma unroll
      for (int tj = 0; tj < 2; ++tj) {
        int wi = ((h * 2 + tj) * 4 + kk) * 64 + lane;
        bf16x8 wb = wpP[wi];
#pragma unroll
        for (int ti = 0; ti < 4; ++ti)
          MFMA16(acc[ti][tj], a[ti], wb);
      }
    }
    float* ow = out + b * 8192;
#pragma unroll
    for (int tj = 0; tj < 2; ++tj) {
      int col = h * 32 + tj * 16 + li;
      float bpv = bp[col];
#pragma unroll
      for (int ti = 0; ti < 4; ++ti)
#pragma unroll
        for (int rr = 0; rr < 4; ++rr) {
          int row = ti * 16 + q4 * 4 + rr;
          ow[row * 128 + col] = acc[ti][tj][rr] + bpv;
        }
    }
  }
}

extern "C" void kernel_launch(void* const* d_in, const int* in_sizes, int n_in,
                              void* d_out, int out_size, void* d_ws, size_t ws_size,
                              hipStream_t stream) {
  (void)in_sizes; (void)n_in; (void)ws_size; (void)out_size;
  prep_kernel<<<96, 256, 0, stream>>>(
      (const float*)d_in[1],   // wq
      (const float*)d_in[3],   // wkv
      (const float*)d_in[6],   // wproj
      (const float*)d_in[5],   // bias_table
      (const int*)d_in[9],     // rel_index
      (char*)d_ws);
  winattn_kernel<<<4096, 256, 0, stream>>>(
      (const float*)d_in[0],   // x
      (const float*)d_in[2],   // bq
      (const float*)d_in[4],   // bkv
      (const float*)d_in[7],   // bproj
      (const float*)d_in[8],   // mask
      (const char*)d_ws,
      (float*)d_out);
}